// Round 2
// baseline (1785.261 us; speedup 1.0000x reference)
//
#include <hip/hip_runtime.h>

// GRUModel: B=4096, H=512, V=512, T=31, D_IN=14
// d_out = [probs: 4096*31*512 f32][hidden: 4096*31*512 f32]
#define NTH 15872   // 31*512

typedef __bf16 bf16x8 __attribute__((ext_vector_type(8)));
typedef float  f32x4  __attribute__((ext_vector_type(4)));

__device__ __forceinline__ unsigned short f2bf(float f) {
    unsigned u = __float_as_uint(f);
    u = u + 0x7fffu + ((u >> 16) & 1u);
    return (unsigned short)(u >> 16);
}
__device__ __forceinline__ float sigm(float x)  { return 1.f / (1.f + __expf(-x)); }
__device__ __forceinline__ float tanhf_(float x){ return 2.f / (1.f + __expf(-2.f * x)) - 1.f; }

// 128B-row LDS tiles (BK=64 bf16), 16B chunks, swizzle: chunk ^= (row&7).
// Write side: 64 lanes cover 8 rows x 8 chunks -> each bank 2 lanes (free).
// Frag read (16 rows, fixed chunk): XOR spreads across all 8 chunks -> uniform
// 8 accesses/bank = wave64-b128 hardware floor.
__device__ __forceinline__ int soff(int r, int kb) { return r * 128 + ((kb ^ (r & 7)) << 4); }

__device__ __forceinline__ int4 pack8(const float* p) {   // 8 f32 -> 8 bf16 (16B)
    float4 a = ((const float4*)p)[0], b = ((const float4*)p)[1];
    union { unsigned short us[8]; int4 v; } u;
    u.us[0]=f2bf(a.x); u.us[1]=f2bf(a.y); u.us[2]=f2bf(a.z); u.us[3]=f2bf(a.w);
    u.us[4]=f2bf(b.x); u.us[5]=f2bf(b.y); u.us[6]=f2bf(b.z); u.us[7]=f2bf(b.w);
    return u.v;
}

// ---------------------------------------------------------------- convert W_hh, W_out -> bf16
__global__ void k_convert(const float* __restrict__ whh, const float* __restrict__ wout,
                          unsigned short* __restrict__ whh_b, unsigned short* __restrict__ wout_b) {
    int i = blockIdx.x * 256 + threadIdx.x;          // 262144 chunks of 4
    const float* s; unsigned short* d; int j;
    if (i < 196608) { s = whh; d = whh_b; j = i; } else { s = wout; d = wout_b; j = i - 196608; }
    float4 v = ((const float4*)s)[j];
    ushort4 o; o.x=f2bf(v.x); o.y=f2bf(v.y); o.z=f2bf(v.z); o.w=f2bf(v.w);
    ((ushort4*)d)[j] = o;
}

// ---------------------------------------------------------------- x = inputs @ W_in.T + b_in -> bf16
__global__ __launch_bounds__(256) void k_linear_in(
    const float* __restrict__ inp, const float* __restrict__ W,
    const float* __restrict__ bias, unsigned short* __restrict__ xb) {
    __shared__ float lW[512 * 14];
    __shared__ float lI[8 * 14];
    const int tid = threadIdx.x, r0 = blockIdx.x * 8;
#pragma unroll
    for (int i = 0; i < 28; ++i) lW[i * 256 + tid] = W[i * 256 + tid];
    if (tid < 112) lI[tid] = inp[r0 * 14 + tid];
    __syncthreads();
#pragma unroll
    for (int i = 0; i < 16; ++i) {
        int idx = i * 256 + tid, r = idx >> 9, j = idx & 511;
        float acc = bias[j];
        const float* wr = lW + j * 14; const float* ir = lI + r * 14;
#pragma unroll
        for (int k = 0; k < 14; ++k) acc += ir[k] * wr[k];
        xb[(size_t)(r0 + r) * 512 + j] = f2bf(acc);
    }
}

// ---------------------------------------------------------------- gi = x @ W_ih.T + (b_ih + b_hh[r,z])
// BM=128, BN=64, BK=64; 4 waves 2x2, wave 64x32. W staged from f32.
__global__ __launch_bounds__(256, 2) void k_gemm_gi(
    const unsigned short* __restrict__ A,   // x_b [4096,512] bf16
    const float* __restrict__ W,            // W_ih [1536,512] f32
    const float* __restrict__ b_ih, const float* __restrict__ b_hh,
    float* __restrict__ C)                  // [4096,1536]
{
    __shared__ __align__(16) char lA[128 * 128];
    __shared__ __align__(16) char lB[64 * 128];
    const int tid = threadIdx.x, lane = tid & 63, wid = tid >> 6;
    const int wm = wid >> 1, wn = wid & 1, hi = lane >> 4, c16 = lane & 15;
    const int m0 = blockIdx.x * 128, n0 = blockIdx.y * 64;
    const char* pa[4]; int la[4];
#pragma unroll
    for (int s = 0; s < 4; ++s) {
        int c = tid + 256 * s, r = c >> 3, kb = c & 7;
        pa[s] = (const char*)A + (size_t)(m0 + r) * 1024 + kb * 16;
        la[s] = soff(r, kb);
    }
    const float* pb[2]; int lb[2];
#pragma unroll
    for (int s = 0; s < 2; ++s) {
        int c = tid + 256 * s, r = c >> 3, kb = c & 7;
        pb[s] = W + (size_t)(n0 + r) * 512 + kb * 8;
        lb[s] = soff(r, kb);
    }
    f32x4 acc[4][2] = {};
    int4 ra[4], rb[2];
#pragma unroll
    for (int s = 0; s < 4; ++s) ra[s] = *(const int4*)pa[s];
#pragma unroll
    for (int s = 0; s < 2; ++s) rb[s] = pack8(pb[s]);
    for (int kt = 0; kt < 8; ++kt) {
        if (kt) __syncthreads();
#pragma unroll
        for (int s = 0; s < 4; ++s) *(int4*)(lA + la[s]) = ra[s];
#pragma unroll
        for (int s = 0; s < 2; ++s) *(int4*)(lB + lb[s]) = rb[s];
        __syncthreads();
        if (kt < 7) {
            int o = (kt + 1) * 128;
#pragma unroll
            for (int s = 0; s < 4; ++s) ra[s] = *(const int4*)(pa[s] + o);
#pragma unroll
            for (int s = 0; s < 2; ++s) rb[s] = pack8(pb[s] + (kt + 1) * 64);
        }
#pragma unroll
        for (int h = 0; h < 2; ++h) {
            bf16x8 af[4];
#pragma unroll
            for (int mf = 0; mf < 4; ++mf)
                af[mf] = *(const bf16x8*)(lA + soff(wm * 64 + mf * 16 + c16, 4 * h + hi));
#pragma unroll
            for (int j = 0; j < 2; ++j) {
                bf16x8 bf_ = *(const bf16x8*)(lB + soff(wn * 32 + j * 16 + c16, 4 * h + hi));
#pragma unroll
                for (int mf = 0; mf < 4; ++mf)
                    acc[mf][j] = __builtin_amdgcn_mfma_f32_16x16x32_bf16(af[mf], bf_, acc[mf][j], 0, 0, 0);
            }
        }
    }
#pragma unroll
    for (int mf = 0; mf < 4; ++mf) {
        int m = m0 + wm * 64 + mf * 16 + hi * 4;
#pragma unroll
        for (int j = 0; j < 2; ++j) {
            int n = n0 + wn * 32 + j * 16 + c16;
            float bj = b_ih[n] + (n < 1024 ? b_hh[n] : 0.f);   // fold b_hh for r,z gates
#pragma unroll
            for (int q = 0; q < 4; ++q) C[(size_t)(m + q) * 1536 + n] = acc[mf][j][q] + bj;
        }
    }
}

// ---------------------------------------------------------------- fused GRU step
// BM=64, BN=64/gate (grid 64x8 = 512 blocks -> 2 blocks/CU), BK=64, 4 waves 1x4
// wave tile 64 rows x 16 cols per gate: per half 7 ds_read / 12 MFMA.
__global__ __launch_bounds__(256, 2) void k_step(
    const unsigned short* __restrict__ Hin, int hstride,   // elems
    const unsigned short* __restrict__ Whh,                // [1536,512] bf16
    const float* __restrict__ gi,                          // [4096,1536] (b_hh folded for r,z)
    const float* __restrict__ bhh,                         // [1536] (n-gate slice used)
    float* __restrict__ hidden,                            // [4096,15872] f32 (d_out)
    unsigned short* __restrict__ Hout, int ostride,        // elems
    int t)
{
    __shared__ __align__(16) char lA[64 * 128];
    __shared__ __align__(16) char lB[192 * 128];
    const int tid = threadIdx.x, lane = tid & 63, w = tid >> 6;
    const int hi = lane >> 4, c16 = lane & 15;
    const int m0 = blockIdx.x * 64, n0 = blockIdx.y * 64;
    f32x4 acc[3][4] = {};
    if (t > 0) {
        const char* pa[2]; int la[2];
#pragma unroll
        for (int s = 0; s < 2; ++s) {
            int c = tid + 256 * s, r = c >> 3, kb = c & 7;
            pa[s] = (const char*)Hin + (size_t)(m0 + r) * ((size_t)hstride * 2) + kb * 16;
            la[s] = soff(r, kb);
        }
        const char* pb[6]; int lb[6];
#pragma unroll
        for (int s = 0; s < 6; ++s) {
            int c = tid + 256 * s, r = c >> 3, kb = c & 7;
            int wrow = ((r >> 6) << 9) + n0 + (r & 63);        // gate*512 + n0 + nl
            pb[s] = (const char*)Whh + (size_t)wrow * 1024 + kb * 16;
            lb[s] = soff(r, kb);
        }
        int4 ra[2], rb[6];
#pragma unroll
        for (int s = 0; s < 2; ++s) ra[s] = *(const int4*)pa[s];
#pragma unroll
        for (int s = 0; s < 6; ++s) rb[s] = *(const int4*)pb[s];
        for (int kt = 0; kt < 8; ++kt) {
            if (kt) __syncthreads();
#pragma unroll
            for (int s = 0; s < 2; ++s) *(int4*)(lA + la[s]) = ra[s];
#pragma unroll
            for (int s = 0; s < 6; ++s) *(int4*)(lB + lb[s]) = rb[s];
            __syncthreads();
            if (kt < 7) {
                int o = (kt + 1) * 128;
#pragma unroll
                for (int s = 0; s < 2; ++s) ra[s] = *(const int4*)(pa[s] + o);
#pragma unroll
                for (int s = 0; s < 6; ++s) rb[s] = *(const int4*)(pb[s] + o);
            }
#pragma unroll
            for (int h = 0; h < 2; ++h) {
                bf16x8 af[4];
#pragma unroll
                for (int mf = 0; mf < 4; ++mf)
                    af[mf] = *(const bf16x8*)(lA + soff(mf * 16 + c16, 4 * h + hi));
#pragma unroll
                for (int g = 0; g < 3; ++g) {
                    bf16x8 bf_ = *(const bf16x8*)(lB + soff(g * 64 + w * 16 + c16, 4 * h + hi));
#pragma unroll
                    for (int mf = 0; mf < 4; ++mf)
                        acc[g][mf] = __builtin_amdgcn_mfma_f32_16x16x32_bf16(af[mf], bf_, acc[g][mf], 0, 0, 0);
                }
            }
        }
    }
    // epilogue
    const int n = n0 + w * 16 + c16;
    const float bn_ = bhh[1024 + n];
#pragma unroll
    for (int mf = 0; mf < 4; ++mf) {
        int mB = m0 + mf * 16 + hi * 4;
#pragma unroll
        for (int q = 0; q < 4; ++q) {
            int m = mB + q;
            const float* gb = gi + (size_t)m * 1536 + n;
            float pr = gb[0]   + acc[0][mf][q];
            float pz = gb[512] + acc[1][mf][q];
            float r  = sigm(pr);
            float z  = sigm(pz);
            float nn = tanhf_(gb[1024] + r * (acc[2][mf][q] + bn_));
            float hold = (t > 0) ? hidden[(size_t)m * NTH + (size_t)(t - 1) * 512 + n] : 0.f;
            float hn = (1.f - z) * nn + z * hold;
            hidden[(size_t)m * NTH + (size_t)t * 512 + n] = hn;
            Hout[(size_t)m * ostride + n] = f2bf(hn);
        }
    }
}

// ---------------------------------------------------------------- projection + softmax
// BM=128, BN=512(all V), BK=64; 512 thr = 8 waves (2x4), wave tile 64x128.
// No max-subtraction: h is tanh-bounded -> |logit| <~ 14, exp safe in f32.
template<bool BF16A>
__global__ __launch_bounds__(512, 2) void k_proj(
    const void* __restrict__ Aptr,          // bf16 [126976,512] or f32 [126976,512]
    const unsigned short* __restrict__ Wo,  // [512,512] bf16
    const float* __restrict__ bo,
    float* __restrict__ out)                // [126976,512]
{
    __shared__ __align__(16) char lA[128 * 128];
    __shared__ __align__(16) char lB[512 * 128];
    __shared__ float red[2][4][64];
    const int tid = threadIdx.x, lane = tid & 63, wid = tid >> 6;
    const int wm = wid >> 2, wn = wid & 3, hi = lane >> 4, c16 = lane & 15;
    const int m0 = blockIdx.x * 128;
    // A staging: 1024 chunks / 512 thr = 2
    const char* pa[2]; const float* pf[2]; int la[2];
#pragma unroll
    for (int s = 0; s < 2; ++s) {
        int c = tid + 512 * s, r = c >> 3, kb = c & 7;
        if (BF16A) pa[s] = (const char*)Aptr + (size_t)(m0 + r) * 1024 + kb * 16;
        else       pf[s] = (const float*)Aptr + (size_t)(m0 + r) * 512 + kb * 8;
        la[s] = soff(r, kb);
    }
    // B staging: 4096 chunks / 512 thr = 8
    const char* pb[8]; int lb[8];
#pragma unroll
    for (int s = 0; s < 8; ++s) {
        int c = tid + 512 * s, r = c >> 3, kb = c & 7;
        pb[s] = (const char*)Wo + (size_t)r * 1024 + kb * 16;
        lb[s] = soff(r, kb);
    }
    f32x4 acc[4][8] = {};
    int4 ra[2], rb[8];
#pragma unroll
    for (int s = 0; s < 2; ++s) ra[s] = BF16A ? *(const int4*)pa[s] : pack8(pf[s]);
#pragma unroll
    for (int s = 0; s < 8; ++s) rb[s] = *(const int4*)pb[s];
    for (int kt = 0; kt < 8; ++kt) {
        if (kt) __syncthreads();
#pragma unroll
        for (int s = 0; s < 2; ++s) *(int4*)(lA + la[s]) = ra[s];
#pragma unroll
        for (int s = 0; s < 8; ++s) *(int4*)(lB + lb[s]) = rb[s];
        __syncthreads();
        if (kt < 7) {
            int o = (kt + 1) * 128;
#pragma unroll
            for (int s = 0; s < 2; ++s) ra[s] = BF16A ? *(const int4*)(pa[s] + o)
                                                     : pack8(pf[s] + (kt + 1) * 64);
#pragma unroll
            for (int s = 0; s < 8; ++s) rb[s] = *(const int4*)(pb[s] + o);
        }
#pragma unroll
        for (int h = 0; h < 2; ++h) {
            bf16x8 af[4];
#pragma unroll
            for (int mf = 0; mf < 4; ++mf)
                af[mf] = *(const bf16x8*)(lA + soff(wm * 64 + mf * 16 + c16, 4 * h + hi));
#pragma unroll
            for (int nf = 0; nf < 8; ++nf) {
                bf16x8 bf_ = *(const bf16x8*)(lB + soff(wn * 128 + nf * 16 + c16, 4 * h + hi));
#pragma unroll
                for (int mf = 0; mf < 4; ++mf)
                    acc[mf][nf] = __builtin_amdgcn_mfma_f32_16x16x32_bf16(af[mf], bf_, acc[mf][nf], 0, 0, 0);
            }
        }
    }
    // bias + exp + per-wave row sums
#pragma unroll
    for (int nf = 0; nf < 8; ++nf) {
        float bj = bo[wn * 128 + nf * 16 + c16];
#pragma unroll
        for (int mf = 0; mf < 4; ++mf)
#pragma unroll
            for (int q = 0; q < 4; ++q)
                acc[mf][nf][q] = __expf(acc[mf][nf][q] + bj);
    }
#pragma unroll
    for (int mf = 0; mf < 4; ++mf)
#pragma unroll
        for (int q = 0; q < 4; ++q) {
            float s = 0.f;
#pragma unroll
            for (int nf = 0; nf < 8; ++nf) s += acc[mf][nf][q];
            s += __shfl_xor(s, 1); s += __shfl_xor(s, 2);
            s += __shfl_xor(s, 4); s += __shfl_xor(s, 8);
            if (c16 == 0) red[wm][wn][mf * 16 + hi * 4 + q] = s;
        }
    __syncthreads();
#pragma unroll
    for (int mf = 0; mf < 4; ++mf)
#pragma unroll
        for (int q = 0; q < 4; ++q) {
            int rl = mf * 16 + hi * 4 + q;
            float inv = 1.f / (red[wm][0][rl] + red[wm][1][rl] + red[wm][2][rl] + red[wm][3][rl]);
            int m = m0 + wm * 64 + rl;
            float* orow = out + (size_t)m * 512 + wn * 128 + c16;
#pragma unroll
            for (int nf = 0; nf < 8; ++nf) orow[nf * 16] = acc[mf][nf][q] * inv;
        }
}

// ---------------------------------------------------------------- launch
extern "C" void kernel_launch(void* const* d_in, const int* in_sizes, int n_in,
                              void* d_out, int out_size, void* d_ws, size_t ws_size,
                              hipStream_t stream) {
    const float* inputs = (const float*)d_in[0];
    const float* W_in   = (const float*)d_in[1];
    const float* b_in   = (const float*)d_in[2];
    const float* W_ih   = (const float*)d_in[3];
    const float* b_ih   = (const float*)d_in[4];
    const float* W_hh   = (const float*)d_in[5];
    const float* b_hh   = (const float*)d_in[6];
    const float* W_out  = (const float*)d_in[7];
    const float* b_out  = (const float*)d_in[8];

    float* out    = (float*)d_out;
    float* hidden = out + (size_t)126976 * 512;

    char* ws = (char*)d_ws;
    unsigned short* whh_b  = (unsigned short*)(ws);              // 1.5 MB
    unsigned short* wout_b = (unsigned short*)(ws + 1572864);    // 0.5 MB
    unsigned short* x_b    = (unsigned short*)(ws + 2097152);    // 4 MB
    float*          gi     = (float*)(ws + 6291456);             // 24 MB
    const bool big = ws_size >= 161480704ULL;                    // full bf16 hidden copy fits?
    unsigned short* hbf2 = (unsigned short*)(ws + 31457280);     // big: [126976,512] bf16 (130 MB)
    unsigned short* hb0  = (unsigned short*)(ws + 31457280);     // small: ping-pong 2 x 4 MB
    unsigned short* hb1  = (unsigned short*)(ws + 35651584);

    k_convert<<<1024, 256, 0, stream>>>(W_hh, W_out, whh_b, wout_b);
    k_linear_in<<<512, 256, 0, stream>>>(inputs, W_in, b_in, x_b);
    k_gemm_gi<<<dim3(32, 24), 256, 0, stream>>>(x_b, W_ih, b_ih, b_hh, gi);

    for (int t = 0; t < 31; ++t) {
        const unsigned short* Hin;
        unsigned short* Hout;
        int hs, os;
        if (big) {
            Hin  = hbf2 + (size_t)(t > 0 ? t - 1 : 0) * 512;  hs = NTH;
            Hout = hbf2 + (size_t)t * 512;                     os = NTH;
        } else {
            Hin  = (t & 1) ? hb0 : hb1;  hs = 512;
            Hout = (t & 1) ? hb1 : hb0;  os = 512;
        }
        k_step<<<dim3(64, 8), 256, 0, stream>>>(Hin, hs, whh_b, gi, b_hh,
                                                hidden, Hout, os, t);
    }
    if (big) k_proj<true><<<992, 512, 0, stream>>>(hbf2, wout_b, b_out, out);
    else     k_proj<false><<<992, 512, 0, stream>>>(hidden, wout_b, b_out, out);
}

// Round 4
// 995.959 us; speedup vs baseline: 1.7925x; 1.7925x over previous
//
#include <hip/hip_runtime.h>

// GRUModel: B=4096, H=512, V=512, T=31, D_IN=14
// d_out = [probs: 4096*31*512 f32][hidden: 4096*31*512 f32]
#define NTH 15872   // 31*512

typedef __bf16 bf16x8 __attribute__((ext_vector_type(8)));
typedef float  f32x4  __attribute__((ext_vector_type(4)));

__device__ __forceinline__ unsigned short f2bf(float f) {
    unsigned u = __float_as_uint(f);
    u = u + 0x7fffu + ((u >> 16) & 1u);
    return (unsigned short)(u >> 16);
}
__device__ __forceinline__ float sigm(float x)  { return 1.f / (1.f + __expf(-x)); }
__device__ __forceinline__ float tanhf_(float x){ return 2.f / (1.f + __expf(-2.f * x)) - 1.f; }

// R1-proven LDS tile layout: [rows][32] bf16 (64B rows), 16B chunks,
// chunk ^= (r>>1)&3.
__device__ __forceinline__ int lds_off(int r, int kb) {
    return r * 64 + ((kb ^ ((r >> 1) & 3)) << 4);
}
__device__ __forceinline__ int4 ldg16(const char* g0, int stride, int kbyte, int c) {
    int r = c >> 2, kb = c & 3;
    return *(const int4*)(g0 + (size_t)r * stride + kbyte + kb * 16);
}
__device__ __forceinline__ void sts16(char* lds, int c, int4 v) {
    int r = c >> 2, kb = c & 3;
    *(int4*)(lds + lds_off(r, kb)) = v;
}
__device__ __forceinline__ bf16x8 ldsfrag(const char* lds, int row, int hi) {
    return *(const bf16x8*)(lds + lds_off(row, hi));
}
// load 8 f32 (stride in floats), round to bf16, pack to one 16B chunk
__device__ __forceinline__ int4 ldg16_f32(const float* g0, int stride, int koff, int c) {
    int r = c >> 2, kb = c & 3;
    const float4* p = (const float4*)(g0 + (size_t)r * stride + koff + kb * 8);
    float4 a = p[0], b = p[1];
    union { unsigned short us[8]; int4 v; } u;
    u.us[0]=f2bf(a.x); u.us[1]=f2bf(a.y); u.us[2]=f2bf(a.z); u.us[3]=f2bf(a.w);
    u.us[4]=f2bf(b.x); u.us[5]=f2bf(b.y); u.us[6]=f2bf(b.z); u.us[7]=f2bf(b.w);
    return u.v;
}

// ---------------------------------------------------------------- converts
__global__ void k_f32_to_bf16(const float* __restrict__ in,
                              unsigned short* __restrict__ out, int n4) {
    int i = blockIdx.x * 256 + threadIdx.x;
    if (i < n4) {
        float4 v = ((const float4*)in)[i];
        ushort4 o;
        o.x = f2bf(v.x); o.y = f2bf(v.y); o.z = f2bf(v.z); o.w = f2bf(v.w);
        ((ushort4*)out)[i] = o;
    }
}

// ---------------------------------------------------------------- x = inputs @ W_in.T + b_in  -> bf16
__global__ void k_linear_in(const float* __restrict__ inp,   // [4096,14]
                            const float* __restrict__ W,     // [512,14]
                            const float* __restrict__ bias,  // [512]
                            unsigned short* __restrict__ xb) // [4096,512] bf16
{
    int idx = blockIdx.x * 256 + threadIdx.x;   // b*512 + j
    int b = idx >> 9, j = idx & 511;
    const float* ir = inp + (size_t)b * 14;
    const float* wr = W + (size_t)j * 14;
    float acc = bias[j];
#pragma unroll
    for (int k = 0; k < 14; ++k) acc += ir[k] * wr[k];
    xb[idx] = f2bf(acc);
}

// ---------------------------------------------------------------- gi = x @ W_ih.T + b_ih (f32 out)
// R1-verbatim: BM=128, BN=64, BK=32, 256 thr = 4 waves (2x2), wave tile 64x32
__global__ __launch_bounds__(256) void k_gemm_gi(
    const unsigned short* __restrict__ A,   // [4096,512] bf16
    const unsigned short* __restrict__ W,   // [1536,512] bf16
    const float* __restrict__ bias,         // [1536]
    float* __restrict__ C)                  // [4096,1536]
{
    __shared__ __align__(16) char lA[128 * 64];
    __shared__ __align__(16) char lB[64 * 64];
    const int tid = threadIdx.x, lane = tid & 63, wid = tid >> 6;
    const int wm = wid >> 1, wn = wid & 1, hi = lane >> 4, c16 = lane & 15;
    const int m0 = blockIdx.x * 128, n0 = blockIdx.y * 64;
    const char* ga = (const char*)(A + (size_t)m0 * 512);
    const char* gb = (const char*)(W + (size_t)n0 * 512);
    f32x4 acc[4][2] = {};
    int4 ra0 = ldg16(ga, 1024, 0, tid);
    int4 ra1 = ldg16(ga, 1024, 0, tid + 256);
    int4 rb0 = ldg16(gb, 1024, 0, tid);
    for (int kt = 0; kt < 16; ++kt) {
        if (kt) __syncthreads();
        sts16(lA, tid, ra0); sts16(lA, tid + 256, ra1); sts16(lB, tid, rb0);
        __syncthreads();
        if (kt < 15) {
            int kb = (kt + 1) * 64;
            ra0 = ldg16(ga, 1024, kb, tid);
            ra1 = ldg16(ga, 1024, kb, tid + 256);
            rb0 = ldg16(gb, 1024, kb, tid);
        }
        bf16x8 af[4];
#pragma unroll
        for (int i = 0; i < 4; ++i) af[i] = ldsfrag(lA, wm * 64 + i * 16 + c16, hi);
#pragma unroll
        for (int j = 0; j < 2; ++j) {
            bf16x8 bfr = ldsfrag(lB, wn * 32 + j * 16 + c16, hi);
#pragma unroll
            for (int i = 0; i < 4; ++i)
                acc[i][j] = __builtin_amdgcn_mfma_f32_16x16x32_bf16(af[i], bfr, acc[i][j], 0, 0, 0);
        }
    }
#pragma unroll
    for (int i = 0; i < 4; ++i) {
        int m = m0 + wm * 64 + i * 16 + hi * 4;
#pragma unroll
        for (int j = 0; j < 2; ++j) {
            int n = n0 + wn * 32 + j * 16 + c16;
            float bj = bias[n];
#pragma unroll
            for (int q = 0; q < 4; ++q)
                C[(size_t)(m + q) * 1536 + n] = acc[i][j][q] + bj;
        }
    }
}

// ---------------------------------------------------------------- fused GRU step (R1-verbatim + slab Hout)
// BM=128, BN=64 per gate (grid 32x8), BK=32, 4 waves 2x2, wave 64x32 per gate
__device__ __forceinline__ int4 ldg16B3(const char* gW, int n0, int kbyte, int c) {
    int r = c >> 2, kb = c & 3;                     // r in [0,192): gate = r>>6
    int wrow = ((r >> 6) << 9) + n0 + (r & 63);     // W_hh row
    return *(const int4*)(gW + (size_t)wrow * 1024 + kbyte + kb * 16);
}

__global__ __launch_bounds__(256) void k_step(
    const unsigned short* __restrict__ Hin, int hstride,  // elems
    const unsigned short* __restrict__ Whh,   // [1536,512] bf16
    const float* __restrict__ gi,             // [4096,1536]
    const float* __restrict__ bhh,            // [1536]
    float* __restrict__ hidden,               // [4096, 15872] f32 (d_out region)
    unsigned short* __restrict__ Hout, int ostride,       // elems
    int t)
{
    __shared__ __align__(16) char lA[128 * 64];
    __shared__ __align__(16) char lB[192 * 64];
    const int tid = threadIdx.x, lane = tid & 63, wid = tid >> 6;
    const int wm = wid >> 1, wn = wid & 1, hi = lane >> 4, c16 = lane & 15;
    const int m0 = blockIdx.x * 128, n0 = blockIdx.y * 64;
    f32x4 acc[3][4][2] = {};
    if (t > 0) {
        const char* ga = (const char*)(Hin + (size_t)m0 * hstride);
        const int gas = hstride * 2;              // row stride bytes
        const char* gw = (const char*)Whh;
        int4 ra0 = ldg16(ga, gas, 0, tid);
        int4 ra1 = ldg16(ga, gas, 0, tid + 256);
        int4 rb0 = ldg16B3(gw, n0, 0, tid);
        int4 rb1 = ldg16B3(gw, n0, 0, tid + 256);
        int4 rb2 = ldg16B3(gw, n0, 0, tid + 512);
        for (int kt = 0; kt < 16; ++kt) {
            if (kt) __syncthreads();
            sts16(lA, tid, ra0); sts16(lA, tid + 256, ra1);
            sts16(lB, tid, rb0); sts16(lB, tid + 256, rb1); sts16(lB, tid + 512, rb2);
            __syncthreads();
            if (kt < 15) {
                int kb = (kt + 1) * 64;
                ra0 = ldg16(ga, gas, kb, tid);
                ra1 = ldg16(ga, gas, kb, tid + 256);
                rb0 = ldg16B3(gw, n0, kb, tid);
                rb1 = ldg16B3(gw, n0, kb, tid + 256);
                rb2 = ldg16B3(gw, n0, kb, tid + 512);
            }
            bf16x8 af[4];
#pragma unroll
            for (int i = 0; i < 4; ++i) af[i] = ldsfrag(lA, wm * 64 + i * 16 + c16, hi);
#pragma unroll
            for (int g = 0; g < 3; ++g) {
#pragma unroll
                for (int j = 0; j < 2; ++j) {
                    bf16x8 bfr = ldsfrag(lB, g * 64 + wn * 32 + j * 16 + c16, hi);
#pragma unroll
                    for (int i = 0; i < 4; ++i)
                        acc[g][i][j] = __builtin_amdgcn_mfma_f32_16x16x32_bf16(af[i], bfr, acc[g][i][j], 0, 0, 0);
                }
            }
        }
    }
    // epilogue: gate math
#pragma unroll
    for (int i = 0; i < 4; ++i) {
        int mB = m0 + wm * 64 + i * 16 + hi * 4;
#pragma unroll
        for (int j = 0; j < 2; ++j) {
            int n = n0 + wn * 32 + j * 16 + c16;   // gate-local column 0..511
            float br = bhh[n], bz = bhh[512 + n], bn = bhh[1024 + n];
#pragma unroll
            for (int q = 0; q < 4; ++q) {
                int m = mB + q;
                size_t gb0 = (size_t)m * 1536 + n;
                float pr = gi[gb0]        + acc[0][i][j][q] + br;
                float pz = gi[gb0 + 512]  + acc[1][i][j][q] + bz;
                float r  = sigm(pr);
                float z  = sigm(pz);
                float nn = tanhf_(gi[gb0 + 1024] + r * (acc[2][i][j][q] + bn));
                float hold = (t > 0) ? hidden[(size_t)m * NTH + (size_t)(t - 1) * 512 + n] : 0.f;
                float hn = (1.f - z) * nn + z * hold;
                hidden[(size_t)m * NTH + (size_t)t * 512 + n] = hn;
                Hout[(size_t)m * ostride + n] = f2bf(hn);
            }
        }
    }
}

// ---------------------------------------------------------------- projection + softmax
// BM=64, BN=512 (full V), BK=32, 256 thr = 4 waves in 2x2; wave tile 32x256.
// Per kt per wave: 18 ds_read_b128 / 32 MFMA (R1 was 33/32).
// No max-subtraction: h is tanh-bounded -> |logit| small, exp safe in f32.
// NOTE: hbf2 slab written as hbf2[b*NTH + t*512 + n] IS row-major [126976,512]
// (since (b*31+t)*512 = b*NTH + t*512) -> astr must be 512, NOT NTH.
template<bool BF16A>
__global__ __launch_bounds__(256) void k_proj(
    const void* __restrict__ Aptr,          // bf16 or f32 [126976,512], row stride astr elems
    int astr,
    const unsigned short* __restrict__ Wo,  // [512,512] bf16
    const float* __restrict__ bo,
    float* __restrict__ out)                // [126976,512]
{
    __shared__ __align__(16) char lA[64 * 64];
    __shared__ __align__(16) char lB[512 * 64];
    __shared__ float red[2][2][32];
    const int tid = threadIdx.x, lane = tid & 63, wid = tid >> 6;
    const int wm = wid >> 1, wn = wid & 1, hi = lane >> 4, c16 = lane & 15;
    const int m0 = blockIdx.x * 64;
    const char*  gab = (const char*)Aptr  + (size_t)m0 * astr * 2;   // bf16 path
    const float* gaf = (const float*)Aptr + (size_t)m0 * astr;       // f32 path
    const char*  gb  = (const char*)Wo;
    f32x4 acc[2][16] = {};
    int4 ra = BF16A ? ldg16(gab, astr * 2, 0, tid) : ldg16_f32(gaf, astr, 0, tid);
    int4 rb[8];
#pragma unroll
    for (int s = 0; s < 8; ++s) rb[s] = ldg16(gb, 1024, 0, tid + 256 * s);
    for (int kt = 0; kt < 16; ++kt) {
        if (kt) __syncthreads();
        sts16(lA, tid, ra);
#pragma unroll
        for (int s = 0; s < 8; ++s) sts16(lB, tid + 256 * s, rb[s]);
        __syncthreads();
        if (kt < 15) {
            ra = BF16A ? ldg16(gab, astr * 2, (kt + 1) * 64, tid)
                       : ldg16_f32(gaf, astr, (kt + 1) * 32, tid);
#pragma unroll
            for (int s = 0; s < 8; ++s) rb[s] = ldg16(gb, 1024, (kt + 1) * 64, tid + 256 * s);
        }
        bf16x8 af[2];
#pragma unroll
        for (int mf = 0; mf < 2; ++mf)
            af[mf] = ldsfrag(lA, wm * 32 + mf * 16 + c16, hi);
#pragma unroll
        for (int nf = 0; nf < 16; ++nf) {
            bf16x8 bfr = ldsfrag(lB, wn * 256 + nf * 16 + c16, hi);
#pragma unroll
            for (int mf = 0; mf < 2; ++mf)
                acc[mf][nf] = __builtin_amdgcn_mfma_f32_16x16x32_bf16(af[mf], bfr, acc[mf][nf], 0, 0, 0);
        }
    }
    // bias + exp (in place), per-wave row partial sums
#pragma unroll
    for (int nf = 0; nf < 16; ++nf) {
        float bj = bo[wn * 256 + nf * 16 + c16];
#pragma unroll
        for (int mf = 0; mf < 2; ++mf)
#pragma unroll
            for (int q = 0; q < 4; ++q)
                acc[mf][nf][q] = __expf(acc[mf][nf][q] + bj);
    }
#pragma unroll
    for (int mf = 0; mf < 2; ++mf)
#pragma unroll
        for (int q = 0; q < 4; ++q) {
            float s = 0.f;
#pragma unroll
            for (int nf = 0; nf < 16; ++nf) s += acc[mf][nf][q];
            s += __shfl_xor(s, 1); s += __shfl_xor(s, 2);
            s += __shfl_xor(s, 4); s += __shfl_xor(s, 8);
            if (c16 == 0) red[wm][wn][mf * 16 + hi * 4 + q] = s;
        }
    __syncthreads();
#pragma unroll
    for (int mf = 0; mf < 2; ++mf)
#pragma unroll
        for (int q = 0; q < 4; ++q) {
            int rl = mf * 16 + hi * 4 + q;
            float inv = 1.f / (red[wm][0][rl] + red[wm][1][rl]);
            int m = m0 + wm * 32 + rl;
            float* orow = out + (size_t)m * 512 + wn * 256 + c16;
#pragma unroll
            for (int nf = 0; nf < 16; ++nf) orow[nf * 16] = acc[mf][nf][q] * inv;
        }
}

// ---------------------------------------------------------------- launch
extern "C" void kernel_launch(void* const* d_in, const int* in_sizes, int n_in,
                              void* d_out, int out_size, void* d_ws, size_t ws_size,
                              hipStream_t stream) {
    const float* inputs = (const float*)d_in[0];
    const float* W_in   = (const float*)d_in[1];
    const float* b_in   = (const float*)d_in[2];
    const float* W_ih   = (const float*)d_in[3];
    const float* b_ih   = (const float*)d_in[4];
    const float* W_hh   = (const float*)d_in[5];
    const float* b_hh   = (const float*)d_in[6];
    const float* W_out  = (const float*)d_in[7];
    const float* b_out  = (const float*)d_in[8];

    float* out    = (float*)d_out;
    float* hidden = out + (size_t)126976 * 512;

    char* ws = (char*)d_ws;
    unsigned short* wih_b  = (unsigned short*)(ws);                 // 1.5 MB
    unsigned short* whh_b  = (unsigned short*)(ws + 1572864);       // 1.5 MB
    unsigned short* wout_b = (unsigned short*)(ws + 3145728);       // 0.5 MB
    unsigned short* x_b    = (unsigned short*)(ws + 3670016);       // 4 MB
    float*          gi     = (float*)(ws + 7864320);                // 25.2 MB
    const bool big = ws_size >= 163053568ULL;                       // hbf2 slab fits?
    unsigned short* hbf2   = (unsigned short*)(ws + 33030144);      // big: [126976,512] bf16
    unsigned short* hb0    = (unsigned short*)(ws + 33030144);      // small: ping-pong
    unsigned short* hb1    = (unsigned short*)(ws + 37224448);

    k_f32_to_bf16<<<768, 256, 0, stream>>>(W_ih, wih_b, 196608);
    k_f32_to_bf16<<<768, 256, 0, stream>>>(W_hh, whh_b, 196608);
    k_f32_to_bf16<<<256, 256, 0, stream>>>(W_out, wout_b, 65536);
    k_linear_in<<<8192, 256, 0, stream>>>(inputs, W_in, b_in, x_b);
    k_gemm_gi<<<dim3(32, 24), 256, 0, stream>>>(x_b, wih_b, b_ih, gi);

    for (int t = 0; t < 31; ++t) {
        const unsigned short* Hin;
        unsigned short* Hout;
        int hs, os;
        if (big) {
            Hin  = hbf2 + (size_t)(t > 0 ? t - 1 : 0) * 512;  hs = NTH;
            Hout = hbf2 + (size_t)t * 512;                     os = NTH;
        } else {
            Hin  = (t & 1) ? hb0 : hb1;  hs = 512;
            Hout = (t & 1) ? hb1 : hb0;  os = 512;
        }
        k_step<<<dim3(32, 8), 256, 0, stream>>>(Hin, hs, whh_b, gi, b_hh,
                                                hidden, Hout, os, t);
    }
    // hbf2 viewed as [126976,512] row-major has row stride 512 (see note above)
    if (big) k_proj<true><<<1984, 256, 0, stream>>>(hbf2, 512, wout_b, b_out, out);
    else     k_proj<false><<<1984, 256, 0, stream>>>(hidden, 512, wout_b, b_out, out);
}